// Round 11
// baseline (170.859 us; speedup 1.0000x reference)
//
#include <hip/hip_runtime.h>
#include <math.h>

#define NEXP 8
#define DIN 128
#define ISZ 16
#define TT 8                       // tokens per wave
#define NWAVE 4
#define TOK_PER_BLK (TT * NWAVE)   // 32
#define NTOK (16 * 4096)           // 65536

typedef float f32x4 __attribute__((ext_vector_type(4)));
typedef unsigned int u32;
typedef u32 u32x4 __attribute__((ext_vector_type(4)));

#define LDS_GY_F32 (TOK_PER_BLK * DIN)   // 4096 floats = 16 KB (only LDS user)
#define SMEM_BYTES (LDS_GY_F32 * 4)

__device__ __forceinline__ u32 pack_bf16(float lo, float hi) {
    u32 a = (__float_as_uint(lo) + 0x8000u) >> 16;          // round-half-up bf16
    u32 b = (__float_as_uint(hi) + 0x8000u) & 0xffff0000u;
    return b | a;
}
__device__ __forceinline__ float bf_lo(u32 v) { return __uint_as_float(v << 16); }
__device__ __forceinline__ float bf_hi(u32 v) { return __uint_as_float(v & 0xffff0000u); }

// ---- pack both weight tensors into bf16 d_ws buffers ----
// P  [idx<8192]:  P[c4*256 + lane*4 + k] = pack(w1[e][4c4+k][2g], w1[e][4c4+k][2g+1])
//                 with lane = e*8+g  (GEMM1: one u32x4 per lane per c4)
// W2P[idx<8192]:  W2P[e*1024 + i2*128 + c] = pack(w2[e][2i2][c], w2[e][2i2+1][c])
__global__ void pack_weights_kernel(const float* __restrict__ w1,
                                    const float* __restrict__ w2,
                                    u32* __restrict__ P,
                                    u32* __restrict__ W2P) {
    int idx = blockIdx.x * 256 + threadIdx.x;       // 0 .. 16383
    if (idx < 8192) {
        int c4 = idx >> 8;
        int r  = idx & 255;
        int ln = r >> 2;
        int k  = r & 3;
        int e  = ln >> 3;
        int g  = ln & 7;
        const float* src = w1 + e * 2048 + (4 * c4 + k) * 16 + 2 * g;
        P[idx] = pack_bf16(src[0], src[1]);
    } else {
        int j  = idx - 8192;                        // 0 .. 8191
        int e  = j >> 10;
        int r  = j & 1023;
        int i2 = r >> 7;
        int c  = r & 127;
        const float* src = w2 + e * 2048 + (2 * i2) * 128 + c;
        W2P[j] = pack_bf16(src[0], src[128]);
    }
}

__global__ __launch_bounds__(256, 1) __attribute__((amdgpu_num_vgpr(96)))
void moe_fused_kernel(
    const float* __restrict__ x,
    const float* __restrict__ rw,
    const u32*   __restrict__ P,     // packed bf16 w1 (32 KB, d_ws)
    const u32*   __restrict__ W2P,   // packed bf16 w2 row-pairs (32 KB, d_ws)
    float* __restrict__ out_agg,
    float* __restrict__ out_exp)
{
    extern __shared__ float lds[];
    float* gys = lds;                          // [32 tok][128] gelu(y)

    const int tid  = threadIdx.x;
    const int wave = tid >> 6;
    const int lane = tid & 63;
    const int btok = blockIdx.x * TOK_PER_BLK;
    const int wtok = btok + wave * TT;

    float* gyw = gys + wave * TT * DIN;        // wave-private gy slice

    // ================= GEMM1: y[t][e][i] = x . w1 =================
    // lane -> (e1 = lane>>3, g = lane&7); computes i = 2g, 2g+1 for 8 tokens.
    const int e1 = lane >> 3;
    const int g  = lane & 7;

    float y0[TT], y1[TT];
#pragma unroll
    for (int t = 0; t < TT; ++t) { y0[t] = 0.f; y1[t] = 0.f; }

    const u32* Pl = P + lane * 4;
    const int xoff = __builtin_amdgcn_readfirstlane(wtok * DIN);
    const float* xu = x + xoff;                // wave-uniform base -> scalar loads

#pragma unroll 1
    for (int c4 = 0; c4 < 32; ++c4) {
        u32x4 u = *(const u32x4*)(Pl + c4 * 256);
        float wa0 = bf_lo(u.x), wb0 = bf_hi(u.x);
        float wa1 = bf_lo(u.y), wb1 = bf_hi(u.y);
        float wa2 = bf_lo(u.z), wb2 = bf_hi(u.z);
        float wa3 = bf_lo(u.w), wb3 = bf_hi(u.w);
#pragma unroll
        for (int t = 0; t < TT; ++t) {
            float x0 = xu[t * DIN + c4 * 4 + 0];   // uniform -> scalar pipe
            float x1 = xu[t * DIN + c4 * 4 + 1];
            float x2 = xu[t * DIN + c4 * 4 + 2];
            float x3 = xu[t * DIN + c4 * 4 + 3];
            y0[t] += x0 * wa0 + x1 * wa1 + x2 * wa2 + x3 * wa3;
            y1[t] += x0 * wb0 + x1 * wb1 + x2 * wb2 + x3 * wb3;
        }
    }

    // ---- exact GELU -> wave-private LDS slice (same-wave consumer, no barrier) ----
#pragma unroll
    for (int t = 0; t < TT; ++t) {
        float a = y0[t], b = y1[t];
        a = 0.5f * a * (1.f + erff(a * 0.70710678118654752f));
        b = 0.5f * b * (1.f + erff(b * 0.70710678118654752f));
        *(float2*)(gyw + t * DIN + e1 * ISZ + 2 * g) = make_float2(a, b);
    }

    // ================= GEMM2 (bf16 w2 from global) + weighted agg =================
    // lane -> q = lane&31 (channel quad), h = lane>>5 (expert parity)
    const int q = lane & 31;
    const int h = lane >> 5;
    const int c4s = q * 4;
    const u32* w2h = W2P + h * 1024 + q * 4;   // expert e=2k+h -> + k*2048
    const f32x4 vzero = (f32x4)(0.f);

#pragma unroll
    for (int th = 0; th < 2; ++th) {           // two 4-token halves
        f32x4 acc[4], agg[4];
#pragma unroll
        for (int t = 0; t < 4; ++t) { acc[t] = vzero; agg[t] = vzero; }

        // prime ch=0 (k=0, i4=0): row-pairs (0,1) and (2,3) of expert h
        u32x4 qA = *(const u32x4*)(w2h + 0);
        u32x4 qB = *(const u32x4*)(w2h + 128);

#pragma unroll 1
        for (int ch = 0; ch < 16; ++ch) {      // (k = ch>>2, i4 = ch&3)
            const int k  = ch >> 2;
            const int i4 = ch & 3;
            const int nch = (ch < 15) ? ch + 1 : 15;   // clamped prefetch
            const u32* nb = w2h + (nch >> 2) * 2048 + (nch & 3) * 256;
            u32x4 nA = *(const u32x4*)nb;
            u32x4 nB = *(const u32x4*)(nb + 128);

            // unpack rows 4*i4 .. 4*i4+3 (quad c4s) from bf16 pairs
            f32x4 w0r = {bf_lo(qA.x), bf_lo(qA.y), bf_lo(qA.z), bf_lo(qA.w)};
            f32x4 w1r = {bf_hi(qA.x), bf_hi(qA.y), bf_hi(qA.z), bf_hi(qA.w)};
            f32x4 w2r = {bf_lo(qB.x), bf_lo(qB.y), bf_lo(qB.z), bf_lo(qB.w)};
            f32x4 w3r = {bf_hi(qB.x), bf_hi(qB.y), bf_hi(qB.z), bf_hi(qB.w)};

            const int e = 2 * k + h;
#pragma unroll
            for (int t = 0; t < 4; ++t) {
                f32x4 gv = *(const f32x4*)(gyw + (th * 4 + t) * DIN + e * ISZ + i4 * 4);
                acc[t] += w0r * gv.x + w1r * gv.y + w2r * gv.z + w3r * gv.w;
            }

            if (i4 == 3) {   // expert e complete: store + weighted agg + reset
#pragma unroll
                for (int t = 0; t < 4; ++t) {
                    const int gtok = wtok + th * 4 + t;
                    *(f32x4*)(out_exp + (size_t)gtok * (NEXP * DIN) + e * DIN + c4s)
                        = acc[t];                        // plain cached store
                    float r = rw[(size_t)gtok * NEXP + e];
                    agg[t] += r * acc[t];
                    acc[t] = vzero;
                }
            }
            qA = nA; qB = nB;
        }

        // combine expert parities: lane l (+) lane l^32, then lanes 0..31 write
#pragma unroll
        for (int t = 0; t < 4; ++t) {
            agg[t].x += __shfl_xor(agg[t].x, 32);
            agg[t].y += __shfl_xor(agg[t].y, 32);
            agg[t].z += __shfl_xor(agg[t].z, 32);
            agg[t].w += __shfl_xor(agg[t].w, 32);
        }
        if (h == 0) {
#pragma unroll
            for (int t = 0; t < 4; ++t) {
                const int gtok = wtok + th * 4 + t;
                *(f32x4*)(out_agg + (size_t)gtok * DIN + c4s) = agg[t];  // plain store
            }
        }
    }
}

extern "C" void kernel_launch(void* const* d_in, const int* in_sizes, int n_in,
                              void* d_out, int out_size, void* d_ws, size_t ws_size,
                              hipStream_t stream) {
    const float* x  = (const float*)d_in[0];
    const float* rw = (const float*)d_in[1];
    const float* w1 = (const float*)d_in[2];
    const float* w2 = (const float*)d_in[3];

    float* out_agg = (float*)d_out;                  // [NTOK][128]
    float* out_exp = out_agg + (size_t)NTOK * DIN;   // [NTOK][8][128]
    u32* P   = (u32*)d_ws;                           // 32 KB packed bf16 w1
    u32* W2P = P + 8192;                             // 32 KB packed bf16 w2

    pack_weights_kernel<<<dim3(64), dim3(256), 0, stream>>>(w1, w2, P, W2P);

    dim3 grid(NTOK / TOK_PER_BLK);   // 2048
    dim3 block(256);
    moe_fused_kernel<<<grid, block, SMEM_BYTES, stream>>>(
        x, rw, P, W2P, out_agg, out_exp);
}

// Round 13
// 130.708 us; speedup vs baseline: 1.3072x; 1.3072x over previous
//
#include <hip/hip_runtime.h>
#include <math.h>

#define NEXP 8
#define DIN 128
#define ISZ 16
#define NTOK (16 * 4096)           // 65536
// wave = 16 tokens, block = 4 waves = 64 tokens, grid = 1024

typedef float f32x4 __attribute__((ext_vector_type(4)));
typedef unsigned int u32;
typedef u32 u32x2 __attribute__((ext_vector_type(2)));
typedef u32 u32x4 __attribute__((ext_vector_type(4)));
typedef short short8 __attribute__((ext_vector_type(8)));

__device__ __forceinline__ u32 pk2(float lo, float hi) {
    // two bf16 (round-half-up): lo -> low 16 bits, hi -> high 16 bits
    return ((__float_as_uint(hi) + 0x8000u) & 0xffff0000u) |
           ((__float_as_uint(lo) + 0x8000u) >> 16);
}

// ---- pack w1/w2 into MFMA fragment order (bf16) in d_ws ----
// Layout principle: HW pairs A-position (lane-group q, elem j) with B-position
// (q, j); the contraction is invariant to WHICH k the HW calls that position,
// as long as A and B packs use the same position->channel map.
//
// P1 (8192 u32): GEMM1 A-frags. entry (nb*4+kb)*64 + l, reg c holds bf16 pair
//   (w1[nb][ch][i], w1[nb][ch+1][i]) with ch = kb*32 + (l>>4)*8 + 2c, i = l&15.
//   (position map f1(q,j) = ch = kb*32 + 8q + j; B1 built at runtime with same)
// P2 (8192 u32): GEMM2 B-frags, K=32 padded. entry (e*8+cb)*64 + l, reg c(0,1)
//   holds pair (w2[e][i][outc], w2[e][i+1][outc]) with i = (l>>4)*4 + 2c,
//   outc = cb*16 + (l&15). Positions j>=4 are synthesized zeros in-kernel.
//   (position map f2(q,j<4) = i = 4q+j == GEMM1's C-row map -> A2 is c1 in-lane)
__global__ void pack_weights_kernel(const float* __restrict__ w1,
                                    const float* __restrict__ w2,
                                    u32* __restrict__ P1u,
                                    u32* __restrict__ P2u) {
    int idx = blockIdx.x * 256 + threadIdx.x;       // 0 .. 16383
    if (idx < 8192) {
        int c     = idx & 3;
        int entry = idx >> 2;
        int l     = entry & 63;
        int nbkb  = entry >> 6;            // 0..31
        int nb = nbkb >> 2, kb = nbkb & 3;
        int qq = l >> 4, row = l & 15;
        int ch = kb * 32 + qq * 8 + 2 * c;
        const float* s = w1 + nb * 2048 + ch * 16 + row;
        P1u[idx] = pk2(s[0], s[16]);
    } else {
        int j     = idx - 8192;            // 0 .. 8191
        int c     = j & 1;                 // reg 0/1
        int entry = j >> 1;                // 0 .. 4095
        int l     = entry & 63;
        int ecb   = entry >> 6;            // 0..63
        int e = ecb >> 3, cb = ecb & 7;
        int qq = l >> 4;
        int i0 = qq * 4 + 2 * c;
        int outc = cb * 16 + (l & 15);
        const float* s = w2 + e * 2048 + i0 * 128 + outc;
        P2u[j] = pk2(s[0], s[128]);
    }
}

__global__ __launch_bounds__(256, 1) __attribute__((amdgpu_num_vgpr(128)))
void moe_mfma_kernel(
    const float* __restrict__ x,
    const float* __restrict__ rw,
    const unsigned short* __restrict__ P1,   // packed w1 frags
    const unsigned short* __restrict__ P2,   // packed w2 frags (K=16 real rows)
    float* __restrict__ out_agg,
    float* __restrict__ out_exp)
{
    const int tid  = threadIdx.x;
    const int wave = tid >> 6;
    const int lane = tid & 63;
    const int q    = lane >> 4;
    const int n16  = lane & 15;
    const int wtok = blockIdx.x * 64 + wave * 16;

    // ---- B1 frags: position (q,j) of kb-block holds x[wtok+n16][kb*32+q*8+j] ----
    short8 b1[4];
    {
        const float* xb = x + (size_t)(wtok + n16) * DIN + q * 8;
#pragma unroll
        for (int kb = 0; kb < 4; ++kb) {
            f32x4 lo = *(const f32x4*)(xb + kb * 32);
            f32x4 hi = *(const f32x4*)(xb + kb * 32 + 4);
            u32x4 u;
            u.x = pk2(lo.x, lo.y); u.y = pk2(lo.z, lo.w);
            u.z = pk2(hi.x, hi.y); u.w = pk2(hi.z, hi.w);
            b1[kb] = __builtin_bit_cast(short8, u);
        }
    }

    // ---- GEMM1 (swapped): c1[e][r] = y[tok=n16][e][i=4q+r]  (verified C/D map) ----
    const short8* P1f = (const short8*)P1;
    f32x4 c1[8];
#pragma unroll
    for (int nb = 0; nb < 8; ++nb) {
        f32x4 a = {0.f, 0.f, 0.f, 0.f};
#pragma unroll
        for (int kb = 0; kb < 4; ++kb) {
            short8 af = P1f[(nb * 4 + kb) * 64 + lane];
            a = __builtin_amdgcn_mfma_f32_16x16x32_bf16(af, b1[kb], a, 0, 0, 0);
        }
        c1[nb] = a;
    }

    // ---- exact GELU + bf16 pack: pa[e] = pairs (gy[i=4q+0,1], gy[i=4q+2,3]) ----
    u32x2 pa[8];
#pragma unroll
    for (int e = 0; e < 8; ++e) {
        float g0 = c1[e][0], g1 = c1[e][1], g2 = c1[e][2], g3 = c1[e][3];
        g0 = 0.5f * g0 * (1.f + erff(g0 * 0.70710678118654752f));
        g1 = 0.5f * g1 * (1.f + erff(g1 * 0.70710678118654752f));
        g2 = 0.5f * g2 * (1.f + erff(g2 * 0.70710678118654752f));
        g3 = 0.5f * g3 * (1.f + erff(g3 * 0.70710678118654752f));
        pa[e].x = pk2(g0, g1);
        pa[e].y = pk2(g2, g3);
    }

    // ---- GEMM2: A2 = c1-derived in-lane (positions j<4); j>=4 = garbage x 0 ----
    const u32x2* P2f = (const u32x2*)P2;
    f32x4 agg[8];
#pragma unroll
    for (int cb = 0; cb < 8; ++cb) agg[cb] = (f32x4){0.f, 0.f, 0.f, 0.f};

    const int tokr = wtok + q * 4;          // + r = this lane's output tokens

#pragma unroll
    for (int e = 0; e < 8; ++e) {
        u32x4 au = {pa[e].x, pa[e].y, pa[e].x, pa[e].y};   // hi half: don't-care
        short8 a2 = __builtin_bit_cast(short8, au);

        f32x4 rwe;
        rwe.x = rw[(size_t)(tokr + 0) * NEXP + e];
        rwe.y = rw[(size_t)(tokr + 1) * NEXP + e];
        rwe.z = rw[(size_t)(tokr + 2) * NEXP + e];
        rwe.w = rw[(size_t)(tokr + 3) * NEXP + e];

        float* oe = out_exp + (size_t)tokr * (NEXP * DIN) + e * DIN + n16;
#pragma unroll
        for (int cb = 0; cb < 8; ++cb) {
            u32x2 w = P2f[(e * 8 + cb) * 64 + lane];
            u32x4 bu = {w.x, w.y, 0u, 0u};                 // hi half: zero rows
            short8 b2 = __builtin_bit_cast(short8, bu);
            f32x4 z = {0.f, 0.f, 0.f, 0.f};
            f32x4 o = __builtin_amdgcn_mfma_f32_16x16x32_bf16(a2, b2, z, 0, 0, 0);
            // C2: row tok = tokr + r, col = e*128 + cb*16 + n16
            __builtin_nontemporal_store(o[0], oe + cb * 16 + 0 * (NEXP * DIN));
            __builtin_nontemporal_store(o[1], oe + cb * 16 + 1 * (NEXP * DIN));
            __builtin_nontemporal_store(o[2], oe + cb * 16 + 2 * (NEXP * DIN));
            __builtin_nontemporal_store(o[3], oe + cb * 16 + 3 * (NEXP * DIN));
            agg[cb] += rwe * o;
        }
    }

    // ---- agg stores: out_agg[tokr + r][cb*16 + n16] ----
    float* oa = out_agg + (size_t)tokr * DIN + n16;
#pragma unroll
    for (int cb = 0; cb < 8; ++cb) {
        __builtin_nontemporal_store(agg[cb][0], oa + cb * 16 + 0 * DIN);
        __builtin_nontemporal_store(agg[cb][1], oa + cb * 16 + 1 * DIN);
        __builtin_nontemporal_store(agg[cb][2], oa + cb * 16 + 2 * DIN);
        __builtin_nontemporal_store(agg[cb][3], oa + cb * 16 + 3 * DIN);
    }
}

extern "C" void kernel_launch(void* const* d_in, const int* in_sizes, int n_in,
                              void* d_out, int out_size, void* d_ws, size_t ws_size,
                              hipStream_t stream) {
    const float* x  = (const float*)d_in[0];
    const float* rw = (const float*)d_in[1];
    const float* w1 = (const float*)d_in[2];
    const float* w2 = (const float*)d_in[3];

    float* out_agg = (float*)d_out;                  // [NTOK][128]
    float* out_exp = out_agg + (size_t)NTOK * DIN;   // [NTOK][8][128]
    u32* P1u = (u32*)d_ws;                           // 32 KB w1 frags
    u32* P2u = P1u + 8192;                           // 32 KB w2 frags

    pack_weights_kernel<<<dim3(64), dim3(256), 0, stream>>>(w1, w2, P1u, P2u);

    dim3 grid(NTOK / 64);   // 1024
    dim3 block(256);
    moe_mfma_kernel<<<grid, block, 0, stream>>>(
        x, rw, (const unsigned short*)P1u, (const unsigned short*)P2u,
        out_agg, out_exp);
}

// Round 14
// 116.084 us; speedup vs baseline: 1.4719x; 1.1260x over previous
//
#include <hip/hip_runtime.h>
#include <math.h>

#define NEXP 8
#define DIN 128
#define NTOK (16 * 4096)           // 65536
// wave = 16 tokens, block = 4 waves = 64 tokens, grid = 1024

typedef float f32x4 __attribute__((ext_vector_type(4)));
typedef unsigned int u32;
typedef u32 u32x2 __attribute__((ext_vector_type(2)));
typedef u32 u32x4 __attribute__((ext_vector_type(4)));
typedef short short8 __attribute__((ext_vector_type(8)));

__device__ __forceinline__ u32 pk2(float lo, float hi) {
    // two bf16 (round-half-up): lo -> low 16 bits, hi -> high 16 bits
    return ((__float_as_uint(hi) + 0x8000u) & 0xffff0000u) |
           ((__float_as_uint(lo) + 0x8000u) >> 16);
}

// ---- pack w1/w2 into MFMA fragment order (bf16) in d_ws ----
// P1 (8192 u32): GEMM1 A-frags (unchanged from r13, verified):
//   entry (nb*4+kb)*64+l, reg c: pair (w1[nb][ch][i], w1[nb][ch+1][i]),
//   ch = kb*32 + (l>>4)*8 + 2c, i = l&15.
// P2 (8192 u32): GEMM2 A-frags (w2), u32x4 per lane covering cb pair:
//   P2[((e*4+cp)*64+l)*4 + c2] with s=c2>>1, c=c2&1:
//   pair (w2[e][i0][outc], w2[e][i0+1][outc]), i0=(l>>4)*4+2c,
//   outc = (2cp+s)*16 + (l&15).  (K=32 positions j>=4 synthesized zero in-kernel)
__global__ void pack_weights_kernel(const float* __restrict__ w1,
                                    const float* __restrict__ w2,
                                    u32* __restrict__ P1u,
                                    u32* __restrict__ P2u) {
    int idx = blockIdx.x * 256 + threadIdx.x;       // 0 .. 16383
    if (idx < 8192) {
        int c     = idx & 3;
        int entry = idx >> 2;
        int l     = entry & 63;
        int nbkb  = entry >> 6;            // 0..31
        int nb = nbkb >> 2, kb = nbkb & 3;
        int qq = l >> 4, row = l & 15;
        int ch = kb * 32 + qq * 8 + 2 * c;
        const float* s = w1 + nb * 2048 + ch * 16 + row;
        P1u[idx] = pk2(s[0], s[16]);
    } else {
        int j     = idx - 8192;            // 0 .. 8191
        int c2    = j & 3;
        int entry = j >> 2;                // 0 .. 2047
        int l     = entry & 63;
        int ecp   = entry >> 6;            // 0..31
        int e = ecp >> 2, cp = ecp & 3;
        int s = c2 >> 1, c = c2 & 1;
        int i0 = (l >> 4) * 4 + 2 * c;
        int outc = (2 * cp + s) * 16 + (l & 15);
        const float* src = w2 + e * 2048 + i0 * 128 + outc;
        P2u[j] = pk2(src[0], src[128]);
    }
}

__global__ __launch_bounds__(256, 1) __attribute__((amdgpu_num_vgpr(128)))
void moe_mfma_kernel(
    const float* __restrict__ x,
    const float* __restrict__ rw,
    const unsigned short* __restrict__ P1,   // packed w1 frags
    const u32* __restrict__ P2,              // packed w2 frags (u32x4/lane)
    float* __restrict__ out_agg,
    float* __restrict__ out_exp)
{
    const int tid  = threadIdx.x;
    const int wave = tid >> 6;
    const int lane = tid & 63;
    const int q    = lane >> 4;
    const int n16  = lane & 15;
    const int wtok = blockIdx.x * 64 + wave * 16;

    // ---- B1 frags: position (q,j) of kb-block = x[wtok+n16][kb*32+q*8+j] ----
    short8 b1[4];
    {
        const float* xb = x + (size_t)(wtok + n16) * DIN + q * 8;
#pragma unroll
        for (int kb = 0; kb < 4; ++kb) {
            f32x4 lo = *(const f32x4*)(xb + kb * 32);
            f32x4 hi = *(const f32x4*)(xb + kb * 32 + 4);
            u32x4 u;
            u.x = pk2(lo.x, lo.y); u.y = pk2(lo.z, lo.w);
            u.z = pk2(hi.x, hi.y); u.w = pk2(hi.z, hi.w);
            b1[kb] = __builtin_bit_cast(short8, u);
        }
    }

    // ---- GEMM1 (swapped): c1[e][r] = y[tok=n16][e][i=4q+r] (verified) ----
    const short8* P1f = (const short8*)P1;
    f32x4 c1[8];
#pragma unroll
    for (int nb = 0; nb < 8; ++nb) {
        f32x4 a = {0.f, 0.f, 0.f, 0.f};
#pragma unroll
        for (int kb = 0; kb < 4; ++kb) {
            short8 af = P1f[(nb * 4 + kb) * 64 + lane];
            a = __builtin_amdgcn_mfma_f32_16x16x32_bf16(af, b1[kb], a, 0, 0, 0);
        }
        c1[nb] = a;
    }

    // ---- exact GELU + bf16 pack: pa[e] = (gy[4q+0,1], gy[4q+2,3]) for tok n16 ----
    u32x2 pa[8];
#pragma unroll
    for (int e = 0; e < 8; ++e) {
        float g0 = c1[e][0], g1 = c1[e][1], g2 = c1[e][2], g3 = c1[e][3];
        g0 = 0.5f * g0 * (1.f + erff(g0 * 0.70710678118654752f));
        g1 = 0.5f * g1 * (1.f + erff(g1 * 0.70710678118654752f));
        g2 = 0.5f * g2 * (1.f + erff(g2 * 0.70710678118654752f));
        g3 = 0.5f * g3 * (1.f + erff(g3 * 0.70710678118654752f));
        pa[e].x = pk2(g0, g1);
        pa[e].y = pk2(g2, g3);
    }

    // ---- GEMM2 swapped: o = mfma(w2frag, gyfrag) -> C2s[outc=cb*16+4q+r][tok=n16]
    //      -> lane stores 4 CONSECUTIVE outc as one b128 NT store ----
    const u32x4* P2f = (const u32x4*)P2;
    f32x4 aggs[8];
#pragma unroll
    for (int cb = 0; cb < 8; ++cb) aggs[cb] = (f32x4){0.f, 0.f, 0.f, 0.f};

    const size_t tok = (size_t)(wtok + n16);
    float* oe_base = out_exp + tok * (NEXP * DIN) + q * 4;  // + e*128 + cb*16
    const f32x4 z = {0.f, 0.f, 0.f, 0.f};

#pragma unroll
    for (int e = 0; e < 8; ++e) {
        u32x4 au = {pa[e].x, pa[e].y, pa[e].x, pa[e].y};    // hi: don't-care (x0)
        short8 gfrag = __builtin_bit_cast(short8, au);
        const float rwe = rw[tok * NEXP + e];               // lane-token uniform

#pragma unroll
        for (int cp = 0; cp < 4; ++cp) {
            u32x4 W = P2f[(e * 4 + cp) * 64 + lane];
            // cb = 2cp
            {
                u32x4 wu = {W.x, W.y, 0u, 0u};              // hi rows = zero
                short8 wf = __builtin_bit_cast(short8, wu);
                f32x4 o = __builtin_amdgcn_mfma_f32_16x16x32_bf16(wf, gfrag, z, 0, 0, 0);
                __builtin_nontemporal_store(o,
                    (f32x4*)(oe_base + e * DIN + (2 * cp) * 16));
                aggs[2 * cp] += rwe * o;
            }
            // cb = 2cp+1
            {
                u32x4 wu = {W.z, W.w, 0u, 0u};
                short8 wf = __builtin_bit_cast(short8, wu);
                f32x4 o = __builtin_amdgcn_mfma_f32_16x16x32_bf16(wf, gfrag, z, 0, 0, 0);
                __builtin_nontemporal_store(o,
                    (f32x4*)(oe_base + e * DIN + (2 * cp + 1) * 16));
                aggs[2 * cp + 1] += rwe * o;
            }
        }
    }

    // ---- agg stores: out_agg[tok][cb*16 + 4q + r], b128 per cb ----
    float* oa_base = out_agg + tok * DIN + q * 4;
#pragma unroll
    for (int cb = 0; cb < 8; ++cb)
        __builtin_nontemporal_store(aggs[cb], (f32x4*)(oa_base + cb * 16));
}

extern "C" void kernel_launch(void* const* d_in, const int* in_sizes, int n_in,
                              void* d_out, int out_size, void* d_ws, size_t ws_size,
                              hipStream_t stream) {
    const float* x  = (const float*)d_in[0];
    const float* rw = (const float*)d_in[1];
    const float* w1 = (const float*)d_in[2];
    const float* w2 = (const float*)d_in[3];

    float* out_agg = (float*)d_out;                  // [NTOK][128]
    float* out_exp = out_agg + (size_t)NTOK * DIN;   // [NTOK][8][128]
    u32* P1u = (u32*)d_ws;                           // 32 KB w1 frags
    u32* P2u = P1u + 8192;                           // 32 KB w2 frags

    pack_weights_kernel<<<dim3(64), dim3(256), 0, stream>>>(w1, w2, P1u, P2u);

    dim3 grid(NTOK / 64);   // 1024
    dim3 block(256);
    moe_mfma_kernel<<<grid, block, 0, stream>>>(
        x, rw, (const unsigned short*)P1u, P2u, out_agg, out_exp);
}

// Round 15
// 98.715 us; speedup vs baseline: 1.7308x; 1.1759x over previous
//
#include <hip/hip_runtime.h>
#include <math.h>

#define NEXP 8
#define DIN 128
#define NTOK (16 * 4096)           // 65536
// wave = 16 tokens, block = 4 waves = 64 tokens, grid = 1024

typedef float f32x4 __attribute__((ext_vector_type(4)));
typedef unsigned int u32;
typedef u32 u32x2 __attribute__((ext_vector_type(2)));
typedef u32 u32x4 __attribute__((ext_vector_type(4)));
typedef short short8 __attribute__((ext_vector_type(8)));

__device__ __forceinline__ u32 pk2(float lo, float hi) {
    // two bf16 (round-half-up): lo -> low 16 bits, hi -> high 16 bits
    return ((__float_as_uint(hi) + 0x8000u) & 0xffff0000u) |
           ((__float_as_uint(lo) + 0x8000u) >> 16);
}

// ---- pack w1/w2 into MFMA fragment order (bf16) in d_ws ----
// P1 (8192 u32): GEMM1 A-frags (verified r13/r14):
//   entry (nb*4+kb)*64+l, reg c: pair (w1[nb][ch][i], w1[nb][ch+1][i]),
//   ch = kb*32 + (l>>4)*8 + 2c, i = l&15.
// P2 (8192 u32): GEMM2 A-frags (w2), u32x4 per lane covering cb pair:
//   P2[((e*4+cp)*64+l)*4 + c2] with s=c2>>1, c=c2&1:
//   pair (w2[e][i0][outc], w2[e][i0+1][outc]), i0=(l>>4)*4+2c,
//   outc = (2cp+s)*16 + (l&15).  (K=32 positions j>=4 synthesized zero in-kernel)
__global__ void pack_weights_kernel(const float* __restrict__ w1,
                                    const float* __restrict__ w2,
                                    u32* __restrict__ P1u,
                                    u32* __restrict__ P2u) {
    int idx = blockIdx.x * 256 + threadIdx.x;       // 0 .. 16383
    if (idx < 8192) {
        int c     = idx & 3;
        int entry = idx >> 2;
        int l     = entry & 63;
        int nbkb  = entry >> 6;            // 0..31
        int nb = nbkb >> 2, kb = nbkb & 3;
        int qq = l >> 4, row = l & 15;
        int ch = kb * 32 + qq * 8 + 2 * c;
        const float* s = w1 + nb * 2048 + ch * 16 + row;
        P1u[idx] = pk2(s[0], s[16]);
    } else {
        int j     = idx - 8192;            // 0 .. 8191
        int c2    = j & 3;
        int entry = j >> 2;                // 0 .. 2047
        int l     = entry & 63;
        int ecp   = entry >> 6;            // 0..31
        int e = ecp >> 2, cp = ecp & 3;
        int s = c2 >> 1, c = c2 & 1;
        int i0 = (l >> 4) * 4 + 2 * c;
        int outc = (2 * cp + s) * 16 + (l & 15);
        const float* src = w2 + e * 2048 + i0 * 128 + outc;
        P2u[j] = pk2(src[0], src[128]);
    }
}

__global__ __launch_bounds__(256, 1) __attribute__((amdgpu_num_vgpr(128)))
void moe_mfma_kernel(
    const float* __restrict__ x,
    const float* __restrict__ rw,
    const unsigned short* __restrict__ P1,   // packed w1 frags
    const u32* __restrict__ P2,              // packed w2 frags (u32x4/lane)
    float* __restrict__ out_agg,
    float* __restrict__ out_exp)
{
    const int tid  = threadIdx.x;
    const int wave = tid >> 6;
    const int lane = tid & 63;
    const int q    = lane >> 4;
    const int n16  = lane & 15;
    const int wtok = blockIdx.x * 64 + wave * 16;

    // ---- B1 frags: position (q,j) of kb-block = x[wtok+n16][kb*32+q*8+j] ----
    short8 b1[4];
    {
        const float* xb = x + (size_t)(wtok + n16) * DIN + q * 8;
#pragma unroll
        for (int kb = 0; kb < 4; ++kb) {
            f32x4 lo = *(const f32x4*)(xb + kb * 32);
            f32x4 hi = *(const f32x4*)(xb + kb * 32 + 4);
            u32x4 u;
            u.x = pk2(lo.x, lo.y); u.y = pk2(lo.z, lo.w);
            u.z = pk2(hi.x, hi.y); u.w = pk2(hi.z, hi.w);
            b1[kb] = __builtin_bit_cast(short8, u);
        }
    }

    // ---- GEMM1 (swapped): c1[e][r] = y[tok=n16][e][i=4q+r] (verified) ----
    const short8* P1f = (const short8*)P1;
    f32x4 c1[8];
#pragma unroll
    for (int nb = 0; nb < 8; ++nb) {
        f32x4 a = {0.f, 0.f, 0.f, 0.f};
#pragma unroll
        for (int kb = 0; kb < 4; ++kb) {
            short8 af = P1f[(nb * 4 + kb) * 64 + lane];
            a = __builtin_amdgcn_mfma_f32_16x16x32_bf16(af, b1[kb], a, 0, 0, 0);
        }
        c1[nb] = a;
    }

    // ---- exact GELU + bf16 pack: pa[e] = (gy[4q+0,1], gy[4q+2,3]) for tok n16 ----
    u32x2 pa[8];
#pragma unroll
    for (int e = 0; e < 8; ++e) {
        float g0 = c1[e][0], g1 = c1[e][1], g2 = c1[e][2], g3 = c1[e][3];
        g0 = 0.5f * g0 * (1.f + erff(g0 * 0.70710678118654752f));
        g1 = 0.5f * g1 * (1.f + erff(g1 * 0.70710678118654752f));
        g2 = 0.5f * g2 * (1.f + erff(g2 * 0.70710678118654752f));
        g3 = 0.5f * g3 * (1.f + erff(g3 * 0.70710678118654752f));
        pa[e].x = pk2(g0, g1);
        pa[e].y = pk2(g2, g3);
    }

    // ---- GEMM2 swapped: o = mfma(w2frag, gyfrag) -> C2s[outc=cb*16+4q+r][tok=n16]
    //      -> lane stores 4 CONSECUTIVE outc as one b128 PLAIN store ----
    const u32x4* P2f = (const u32x4*)P2;
    f32x4 aggs[8];
#pragma unroll
    for (int cb = 0; cb < 8; ++cb) aggs[cb] = (f32x4){0.f, 0.f, 0.f, 0.f};

    const size_t tok = (size_t)(wtok + n16);
    float* oe_base = out_exp + tok * (NEXP * DIN) + q * 4;  // + e*128 + cb*16
    const f32x4 z = {0.f, 0.f, 0.f, 0.f};

#pragma unroll
    for (int e = 0; e < 8; ++e) {
        u32x4 au = {pa[e].x, pa[e].y, pa[e].x, pa[e].y};    // hi: don't-care (x0)
        short8 gfrag = __builtin_bit_cast(short8, au);
        const float rwe = rw[tok * NEXP + e];               // lane-token uniform

#pragma unroll
        for (int cp = 0; cp < 4; ++cp) {
            u32x4 W = P2f[(e * 4 + cp) * 64 + lane];
            // cb = 2cp
            {
                u32x4 wu = {W.x, W.y, 0u, 0u};              // hi rows = zero
                short8 wf = __builtin_bit_cast(short8, wu);
                f32x4 o = __builtin_amdgcn_mfma_f32_16x16x32_bf16(wf, gfrag, z, 0, 0, 0);
                *(f32x4*)(oe_base + e * DIN + (2 * cp) * 16) = o;       // plain store
                aggs[2 * cp] += rwe * o;
            }
            // cb = 2cp+1
            {
                u32x4 wu = {W.z, W.w, 0u, 0u};
                short8 wf = __builtin_bit_cast(short8, wu);
                f32x4 o = __builtin_amdgcn_mfma_f32_16x16x32_bf16(wf, gfrag, z, 0, 0, 0);
                *(f32x4*)(oe_base + e * DIN + (2 * cp + 1) * 16) = o;   // plain store
                aggs[2 * cp + 1] += rwe * o;
            }
        }
    }

    // ---- agg stores: out_agg[tok][cb*16 + 4q + r], b128 per cb ----
    float* oa_base = out_agg + tok * DIN + q * 4;
#pragma unroll
    for (int cb = 0; cb < 8; ++cb)
        *(f32x4*)(oa_base + cb * 16) = aggs[cb];            // plain store
}

extern "C" void kernel_launch(void* const* d_in, const int* in_sizes, int n_in,
                              void* d_out, int out_size, void* d_ws, size_t ws_size,
                              hipStream_t stream) {
    const float* x  = (const float*)d_in[0];
    const float* rw = (const float*)d_in[1];
    const float* w1 = (const float*)d_in[2];
    const float* w2 = (const float*)d_in[3];

    float* out_agg = (float*)d_out;                  // [NTOK][128]
    float* out_exp = out_agg + (size_t)NTOK * DIN;   // [NTOK][8][128]
    u32* P1u = (u32*)d_ws;                           // 32 KB w1 frags
    u32* P2u = P1u + 8192;                           // 32 KB w2 frags

    pack_weights_kernel<<<dim3(64), dim3(256), 0, stream>>>(w1, w2, P1u, P2u);

    dim3 grid(NTOK / 64);   // 1024
    dim3 block(256);
    moe_mfma_kernel<<<grid, block, 0, stream>>>(
        x, rw, (const unsigned short*)P1u, P2u, out_agg, out_exp);
}

// Round 16
// 78.584 us; speedup vs baseline: 2.1742x; 1.2562x over previous
//
#include <hip/hip_runtime.h>
#include <math.h>

#define NEXP 8
#define DIN 128
#define NTOK (16 * 4096)           // 65536
// wave = 16 tokens, block = 4 waves = 64 tokens, grid = 1024

#define LPITCH 136                 // LDS pitch (floats) for [16 tok][128 outc] tile
#define LDS_PER_WAVE (16 * LPITCH) // 2176 floats = 8704 B
#define SMEM_BYTES (4 * LDS_PER_WAVE * 4)   // 34816 B

typedef float f32x4 __attribute__((ext_vector_type(4)));
typedef unsigned int u32;
typedef u32 u32x2 __attribute__((ext_vector_type(2)));
typedef u32 u32x4 __attribute__((ext_vector_type(4)));
typedef short short8 __attribute__((ext_vector_type(8)));

__device__ __forceinline__ u32 pk2(float lo, float hi) {
    // two bf16 (round-half-up): lo -> low 16 bits, hi -> high 16 bits
    return ((__float_as_uint(hi) + 0x8000u) & 0xffff0000u) |
           ((__float_as_uint(lo) + 0x8000u) >> 16);
}

// ---- pack w1/w2 into MFMA fragment order (bf16) in d_ws (verified r13-r15) ----
// P1 (8192 u32): GEMM1 A-frags: entry (nb*4+kb)*64+l, reg c: pair
//   (w1[nb][ch][i], w1[nb][ch+1][i]), ch = kb*32 + (l>>4)*8 + 2c, i = l&15.
// P2 (8192 u32): GEMM2 A-frags (w2), u32x4 per lane covering cb pair:
//   P2[((e*4+cp)*64+l)*4 + c2], s=c2>>1, c=c2&1: pair
//   (w2[e][i0][outc], w2[e][i0+1][outc]), i0=(l>>4)*4+2c, outc=(2cp+s)*16+(l&15).
__global__ void pack_weights_kernel(const float* __restrict__ w1,
                                    const float* __restrict__ w2,
                                    u32* __restrict__ P1u,
                                    u32* __restrict__ P2u) {
    int idx = blockIdx.x * 256 + threadIdx.x;       // 0 .. 16383
    if (idx < 8192) {
        int c     = idx & 3;
        int entry = idx >> 2;
        int l     = entry & 63;
        int nbkb  = entry >> 6;            // 0..31
        int nb = nbkb >> 2, kb = nbkb & 3;
        int qq = l >> 4, row = l & 15;
        int ch = kb * 32 + qq * 8 + 2 * c;
        const float* s = w1 + nb * 2048 + ch * 16 + row;
        P1u[idx] = pk2(s[0], s[16]);
    } else {
        int j     = idx - 8192;            // 0 .. 8191
        int c2    = j & 3;
        int entry = j >> 2;                // 0 .. 2047
        int l     = entry & 63;
        int ecp   = entry >> 6;            // 0..31
        int e = ecp >> 2, cp = ecp & 3;
        int s = c2 >> 1, c = c2 & 1;
        int i0 = (l >> 4) * 4 + 2 * c;
        int outc = (2 * cp + s) * 16 + (l & 15);
        const float* src = w2 + e * 2048 + i0 * 128 + outc;
        P2u[j] = pk2(src[0], src[128]);
    }
}

__global__ __launch_bounds__(256, 1) __attribute__((amdgpu_num_vgpr(128)))
void moe_mfma_kernel(
    const float* __restrict__ x,
    const float* __restrict__ rw,
    const unsigned short* __restrict__ P1,   // packed w1 frags
    const u32* __restrict__ P2,              // packed w2 frags (u32x4/lane)
    float* __restrict__ out_agg,
    float* __restrict__ out_exp)
{
    extern __shared__ float lds[];

    const int tid  = threadIdx.x;
    const int wave = tid >> 6;
    const int lane = tid & 63;
    const int q    = lane >> 4;
    const int n16  = lane & 15;
    const int wtok = blockIdx.x * 64 + wave * 16;

    float* Lw = lds + wave * LDS_PER_WAVE;   // wave-private [16][LPITCH] tile

    // ---- B1 frags: position (q,j) of kb-block = x[wtok+n16][kb*32+q*8+j] ----
    short8 b1[4];
    {
        const float* xb = x + (size_t)(wtok + n16) * DIN + q * 8;
#pragma unroll
        for (int kb = 0; kb < 4; ++kb) {
            f32x4 lo = *(const f32x4*)(xb + kb * 32);
            f32x4 hi = *(const f32x4*)(xb + kb * 32 + 4);
            u32x4 u;
            u.x = pk2(lo.x, lo.y); u.y = pk2(lo.z, lo.w);
            u.z = pk2(hi.x, hi.y); u.w = pk2(hi.z, hi.w);
            b1[kb] = __builtin_bit_cast(short8, u);
        }
    }

    // ---- GEMM1 (swapped): c1[e][r] = y[tok=n16][e][i=4q+r] (verified) ----
    const short8* P1f = (const short8*)P1;
    f32x4 c1[8];
#pragma unroll
    for (int nb = 0; nb < 8; ++nb) {
        f32x4 a = {0.f, 0.f, 0.f, 0.f};
#pragma unroll
        for (int kb = 0; kb < 4; ++kb) {
            short8 af = P1f[(nb * 4 + kb) * 64 + lane];
            a = __builtin_amdgcn_mfma_f32_16x16x32_bf16(af, b1[kb], a, 0, 0, 0);
        }
        c1[nb] = a;
    }

    // ---- exact GELU + bf16 pack: pa[e] = (gy[4q+0,1], gy[4q+2,3]) for tok n16 ----
    u32x2 pa[8];
#pragma unroll
    for (int e = 0; e < 8; ++e) {
        float g0 = c1[e][0], g1 = c1[e][1], g2 = c1[e][2], g3 = c1[e][3];
        g0 = 0.5f * g0 * (1.f + erff(g0 * 0.70710678118654752f));
        g1 = 0.5f * g1 * (1.f + erff(g1 * 0.70710678118654752f));
        g2 = 0.5f * g2 * (1.f + erff(g2 * 0.70710678118654752f));
        g3 = 0.5f * g3 * (1.f + erff(g3 * 0.70710678118654752f));
        pa[e].x = pk2(g0, g1);
        pa[e].y = pk2(g2, g3);
    }

    // ---- GEMM2 swapped: o = mfma(w2frag, gyfrag) -> C2s[outc=cb*16+4q+r][tok=n16]
    //      MFMA out -> wave-private LDS (token-major) -> contiguous global stores
    const u32x4* P2f = (const u32x4*)P2;
    f32x4 aggs[8];
#pragma unroll
    for (int cb = 0; cb < 8; ++cb) aggs[cb] = (f32x4){0.f, 0.f, 0.f, 0.f};

    const size_t tok = (size_t)(wtok + n16);
    const f32x4 z = {0.f, 0.f, 0.f, 0.f};
    // read-back/store mapping: instr k covers tokens 2k, 2k+1
    const int rtok = (lane >> 5);            // 0/1: which of the 2 tokens
    const int rc   = (lane & 31) * 4;        // 0..124: outc quad
    const float* rwp = rw + tok * NEXP;

#pragma unroll
    for (int e = 0; e < 8; ++e) {
        u32x4 au = {pa[e].x, pa[e].y, pa[e].x, pa[e].y};    // hi: don't-care (x0)
        short8 gfrag = __builtin_bit_cast(short8, au);
        const float rwe = rwp[e];                           // lane-token uniform

#pragma unroll
        for (int cp = 0; cp < 4; ++cp) {
            u32x4 W = P2f[(e * 4 + cp) * 64 + lane];
            // cb = 2cp
            {
                u32x4 wu = {W.x, W.y, 0u, 0u};              // hi rows = zero
                short8 wf = __builtin_bit_cast(short8, wu);
                f32x4 o = __builtin_amdgcn_mfma_f32_16x16x32_bf16(wf, gfrag, z, 0, 0, 0);
                *(f32x4*)(Lw + n16 * LPITCH + (2 * cp) * 16 + 4 * q) = o;
                aggs[2 * cp] += rwe * o;
            }
            // cb = 2cp+1
            {
                u32x4 wu = {W.z, W.w, 0u, 0u};
                short8 wf = __builtin_bit_cast(short8, wu);
                f32x4 o = __builtin_amdgcn_mfma_f32_16x16x32_bf16(wf, gfrag, z, 0, 0, 0);
                *(f32x4*)(Lw + n16 * LPITCH + (2 * cp + 1) * 16 + 4 * q) = o;
                aggs[2 * cp + 1] += rwe * o;
            }
        }

        // drain expert e: 8 instrs, each storing 2 contiguous 512 B token-rows
        float* oe = out_exp + (size_t)wtok * (NEXP * DIN) + e * DIN;
#pragma unroll
        for (int k = 0; k < 8; ++k) {
            const int t2 = 2 * k + rtok;
            f32x4 v = *(const f32x4*)(Lw + t2 * LPITCH + rc);
            *(f32x4*)(oe + (size_t)t2 * (NEXP * DIN) + rc) = v;
        }
    }

    // ---- agg: same LDS transpose -> contiguous out_agg rows ----
#pragma unroll
    for (int cb = 0; cb < 8; ++cb)
        *(f32x4*)(Lw + n16 * LPITCH + cb * 16 + 4 * q) = aggs[cb];

    float* oa = out_agg + (size_t)wtok * DIN;
#pragma unroll
    for (int k = 0; k < 8; ++k) {
        const int t2 = 2 * k + rtok;
        f32x4 v = *(const f32x4*)(Lw + t2 * LPITCH + rc);
        *(f32x4*)(oa + (size_t)t2 * DIN + rc) = v;
    }
}

extern "C" void kernel_launch(void* const* d_in, const int* in_sizes, int n_in,
                              void* d_out, int out_size, void* d_ws, size_t ws_size,
                              hipStream_t stream) {
    const float* x  = (const float*)d_in[0];
    const float* rw = (const float*)d_in[1];
    const float* w1 = (const float*)d_in[2];
    const float* w2 = (const float*)d_in[3];

    float* out_agg = (float*)d_out;                  // [NTOK][128]
    float* out_exp = out_agg + (size_t)NTOK * DIN;   // [NTOK][8][128]
    u32* P1u = (u32*)d_ws;                           // 32 KB w1 frags
    u32* P2u = P1u + 8192;                           // 32 KB w2 frags

    pack_weights_kernel<<<dim3(64), dim3(256), 0, stream>>>(w1, w2, P1u, P2u);

    dim3 grid(NTOK / 64);   // 1024
    dim3 block(256);
    moe_mfma_kernel<<<grid, block, SMEM_BYTES, stream>>>(
        x, rw, (const unsigned short*)P1u, P2u, out_agg, out_exp);
}